// Round 6
// baseline (3095.240 us; speedup 1.0000x reference)
//
#include <hip/hip_runtime.h>

#define B_    32
#define HW_   3136
#define C_    512
#define H_    128
#define NW_   1024                    // worker blocks
#define NM_   32                      // MLP blocks (one per batch)
#define SL_   392                     // float4 slice per worker per batch (401408/1024)
#define BPB4_ (HW_ * (C_ / 4))        // float4 per batch = 401408

// ctrl dword offsets (64 B padded):
#define CNT8(b,r) (16 * ((b) * 8 + (r)))   // per-(batch, wid%8) counter, 128 workers each
#define CNTB(b)   (4096 + 16 * (b))        // per-batch promoted counter (==8 when ready)
#define FLAG(b)   (4608 + 16 * (b))        // weights-ready flag
#define CTRL_BYTES 20480

// ---------------------------------------------------------------------------
// Fused persistent kernel. Blocks 0..31: MLP for batch b. Blocks 32..1055:
// workers, each owns a fixed 392-float4 slice of every batch.
// Worker loop: stash(b) lives in LDS; regs pre-load b+1 and signal its partial
// while batch b's MLP runs in parallel -> pass2 reads LDS, never re-reads HBM.
// ---------------------------------------------------------------------------
__global__ __launch_bounds__(256, 5) void fused2_kernel(
    const float4* __restrict__ c4,
    const float4* __restrict__ w4,
    const float4* __restrict__ h4,
    float4* __restrict__ o4,
    const float* __restrict__ fc1_w,
    const float* __restrict__ fc1_b,
    const float* __restrict__ fc2_w,
    const float* __restrict__ fc2_b,
    unsigned* __restrict__ ctrl,
    float* __restrict__ partial,      // [2][NW_][C_] double-buffered by b&1
    float* __restrict__ wbuf)         // [B_][3*C_]
{
    __shared__ float4 stash[3 * SL_ + 128];   // c|w|h slices + red[128] = 20.9 KB
    const int t = threadIdx.x;

    if (blockIdx.x < NM_) {
        // ================= MLP block: one batch ============================
        const int b = blockIdx.x;
        if (t == 0) {
            unsigned spin = 0;
            while (__hip_atomic_load(&ctrl[CNTB(b)], __ATOMIC_RELAXED,
                                     __HIP_MEMORY_SCOPE_AGENT) != 8u) {
                __builtin_amdgcn_s_sleep(8);
                if (++spin > (1u << 24)) break;
            }
            __builtin_amdgcn_fence(__ATOMIC_ACQUIRE, "agent");
        }
        __syncthreads();

        float* s_lds = (float*)stash;         // [512]
        float* y_lds = ((float*)stash) + C_;  // [128]
        const float* pb = partial + (size_t)(b & 1) * NW_ * C_;

        for (int c = t; c < C_; c += 256) {
            float a0 = 0.f, a1 = 0.f, a2 = 0.f, a3 = 0.f;
            for (int w = 0; w < NW_; w += 4) {
                a0 += __hip_atomic_load(pb + (size_t)(w + 0) * C_ + c, __ATOMIC_RELAXED, __HIP_MEMORY_SCOPE_AGENT);
                a1 += __hip_atomic_load(pb + (size_t)(w + 1) * C_ + c, __ATOMIC_RELAXED, __HIP_MEMORY_SCOPE_AGENT);
                a2 += __hip_atomic_load(pb + (size_t)(w + 2) * C_ + c, __ATOMIC_RELAXED, __HIP_MEMORY_SCOPE_AGENT);
                a3 += __hip_atomic_load(pb + (size_t)(w + 3) * C_ + c, __ATOMIC_RELAXED, __HIP_MEMORY_SCOPE_AGENT);
            }
            s_lds[c] = ((a0 + a1) + (a2 + a3)) * (1.0f / (float)HW_);
        }
        __syncthreads();

        if (t < H_) {
            float acc = fc1_b[t];
            const float* __restrict__ wr = fc1_w + (long)t * C_;
            #pragma unroll 4
            for (int c = 0; c < C_; ++c) acc += s_lds[c] * wr[c];
            const float x = acc;
            const float u = 0.7978845608028654f * (x + 0.044715f * x * x * x);
            y_lds[t] = 0.5f * x * (1.0f + tanhf(u));
        }
        __syncthreads();

        for (int c = t; c < C_; c += 256) {
            float lg[3];
            #pragma unroll
            for (int j = 0; j < 3; ++j) {
                const int row = j * C_ + c;
                float a2c = fc2_b[row];
                const float* __restrict__ wr = fc2_w + (long)row * H_;
                #pragma unroll 4
                for (int h = 0; h < H_; ++h) a2c += y_lds[h] * wr[h];
                lg[j] = a2c;
            }
            const float m  = fmaxf(lg[0], fmaxf(lg[1], lg[2]));
            const float e0 = __expf(lg[0] - m);
            const float e1 = __expf(lg[1] - m);
            const float e2 = __expf(lg[2] - m);
            const float inv = 1.0f / (e0 + e1 + e2);
            float* wb = wbuf + (long)b * 3 * C_;
            __hip_atomic_store(wb + 0 * C_ + c, e0 * inv, __ATOMIC_RELAXED, __HIP_MEMORY_SCOPE_AGENT);
            __hip_atomic_store(wb + 1 * C_ + c, e1 * inv, __ATOMIC_RELAXED, __HIP_MEMORY_SCOPE_AGENT);
            __hip_atomic_store(wb + 2 * C_ + c, e2 * inv, __ATOMIC_RELAXED, __HIP_MEMORY_SCOPE_AGENT);
        }
        __syncthreads();
        if (t == 0)
            __hip_atomic_store(&ctrl[FLAG(b)], 1u, __ATOMIC_RELEASE, __HIP_MEMORY_SCOPE_AGENT);
        return;
    }

    // ==================== worker block =====================================
    const int wid  = blockIdx.x - NM_;          // 0..1023
    const int col4 = (8 * wid + t) & 127;       // same for elem t and t+256
    const bool two = (t < SL_ - 256);           // t < 136 handles 2nd element
    float4* sc  = stash;
    float4* sw  = stash + SL_;
    float4* sh  = stash + 2 * SL_;
    float4* red = stash + 3 * SL_;

    float4 a0, v0, u0, a1, v1, u1;

    // ---- load batch bb into regs, fold partial, signal counters ----
    #define LOAD_FOLD_SIGNAL(bb)                                                  \
    {                                                                             \
        const long g = (long)(bb) * BPB4_ + (long)wid * SL_;                      \
        a0 = c4[g + t]; v0 = w4[g + t]; u0 = h4[g + t];                           \
        if (two) { a1 = c4[g + t + 256]; v1 = w4[g + t + 256]; u1 = h4[g + t + 256]; } \
        float4 acc;                                                               \
        acc.x = a0.x + v0.x + u0.x; acc.y = a0.y + v0.y + u0.y;                   \
        acc.z = a0.z + v0.z + u0.z; acc.w = a0.w + v0.w + u0.w;                   \
        if (two) {                                                                \
            acc.x += a1.x + v1.x + u1.x; acc.y += a1.y + v1.y + u1.y;             \
            acc.z += a1.z + v1.z + u1.z; acc.w += a1.w + v1.w + u1.w;             \
        }                                                                         \
        if (t >= 128) red[t - 128] = acc;                                         \
        __syncthreads();                                                          \
        if (t < 128) {                                                            \
            const float4 o = red[t];                                              \
            acc.x += o.x; acc.y += o.y; acc.z += o.z; acc.w += o.w;               \
            float* pp = partial + (size_t)((bb) & 1) * NW_ * C_                   \
                      + (size_t)wid * C_ + col4 * 4;                              \
            __hip_atomic_store(pp + 0, acc.x, __ATOMIC_RELAXED, __HIP_MEMORY_SCOPE_AGENT); \
            __hip_atomic_store(pp + 1, acc.y, __ATOMIC_RELAXED, __HIP_MEMORY_SCOPE_AGENT); \
            __hip_atomic_store(pp + 2, acc.z, __ATOMIC_RELAXED, __HIP_MEMORY_SCOPE_AGENT); \
            __hip_atomic_store(pp + 3, acc.w, __ATOMIC_RELAXED, __HIP_MEMORY_SCOPE_AGENT); \
        }                                                                         \
        __syncthreads();                                                          \
        if (t == 0) {                                                             \
            const unsigned old = __hip_atomic_fetch_add(                          \
                &ctrl[CNT8((bb), wid & 7)], 1u, __ATOMIC_ACQ_REL, __HIP_MEMORY_SCOPE_AGENT); \
            if (old == 127u)                                                      \
                __hip_atomic_fetch_add(&ctrl[CNTB(bb)], 1u,                       \
                                       __ATOMIC_ACQ_REL, __HIP_MEMORY_SCOPE_AGENT); \
        }                                                                         \
    }

    #define DUMP_TO_LDS()                                                         \
    {                                                                             \
        sc[t] = a0; sw[t] = v0; sh[t] = u0;                                       \
        if (two) { sc[t + 256] = a1; sw[t + 256] = v1; sh[t + 256] = u1; }        \
    }

    LOAD_FOLD_SIGNAL(0);
    DUMP_TO_LDS();

    for (int b = 0; b < B_; ++b) {
        if (b + 1 < B_) LOAD_FOLD_SIGNAL(b + 1);

        // wait for batch b weights (relaxed poll, one acquire fence)
        if (t == 0) {
            unsigned spin = 0;
            while (__hip_atomic_load(&ctrl[FLAG(b)], __ATOMIC_RELAXED,
                                     __HIP_MEMORY_SCOPE_AGENT) == 0u) {
                __builtin_amdgcn_s_sleep(8);
                if (++spin > (1u << 24)) break;
            }
            __builtin_amdgcn_fence(__ATOMIC_ACQUIRE, "agent");
        }
        __syncthreads();

        // per-thread weights (12 dwords, L1-hot)
        const float* wb = wbuf + (long)b * 3 * C_ + col4 * 4;
        float w0[4], w1[4], w2[4];
        #pragma unroll
        for (int j = 0; j < 4; ++j) {
            w0[j] = __hip_atomic_load(wb + 0 * C_ + j, __ATOMIC_RELAXED, __HIP_MEMORY_SCOPE_AGENT);
            w1[j] = __hip_atomic_load(wb + 1 * C_ + j, __ATOMIC_RELAXED, __HIP_MEMORY_SCOPE_AGENT);
            w2[j] = __hip_atomic_load(wb + 2 * C_ + j, __ATOMIC_RELAXED, __HIP_MEMORY_SCOPE_AGENT);
        }

        // pass 2: LDS stash -> output (thread-private slots, no barrier needed)
        const long obase = (long)b * BPB4_ + (long)wid * SL_;
        {
            const float4 A = sc[t], V = sw[t], U = sh[t];
            float4 o;
            o.x = A.x * w0[0] + V.x * w1[0] + U.x * w2[0];
            o.y = A.y * w0[1] + V.y * w1[1] + U.y * w2[1];
            o.z = A.z * w0[2] + V.z * w1[2] + U.z * w2[2];
            o.w = A.w * w0[3] + V.w * w1[3] + U.w * w2[3];
            o4[obase + t] = o;
        }
        if (two) {
            const float4 A = sc[t + 256], V = sw[t + 256], U = sh[t + 256];
            float4 o;
            o.x = A.x * w0[0] + V.x * w1[0] + U.x * w2[0];
            o.y = A.y * w0[1] + V.y * w1[1] + U.y * w2[1];
            o.z = A.z * w0[2] + V.z * w1[2] + U.z * w2[2];
            o.w = A.w * w0[3] + V.w * w1[3] + U.w * w2[3];
            o4[obase + t + 256] = o;
        }

        if (b + 1 < B_) DUMP_TO_LDS();   // own slots; pass2 of b already consumed them
    }
    #undef LOAD_FOLD_SIGNAL
    #undef DUMP_TO_LDS
}

// ===========================================================================
// Fallback: proven R3 three-kernel path (330 us) if workspace is too small.
// ===========================================================================
#define CHF_ 49
__global__ __launch_bounds__(256) void ps_kernel(
    const float4* __restrict__ c4, const float4* __restrict__ w4,
    const float4* __restrict__ h4, float4* __restrict__ partial)
{
    const int bx = blockIdx.x, b = blockIdx.y, t = threadIdx.x;
    const int col4 = t & 127, rl = t >> 7;
    const int STRIDE = CHF_ * 256;
    long idx = (long)b * BPB4_ + bx * 256 + t;
    float4 acc = make_float4(0.f, 0.f, 0.f, 0.f);
    #pragma unroll 4
    for (int it = 0; it < 32; ++it) {
        const float4 a = c4[idx], v = w4[idx], u = h4[idx];
        acc.x += a.x + v.x + u.x; acc.y += a.y + v.y + u.y;
        acc.z += a.z + v.z + u.z; acc.w += a.w + v.w + u.w;
        idx += STRIDE;
    }
    __shared__ float4 red[128];
    if (rl == 1) red[col4] = acc;
    __syncthreads();
    if (rl == 0) {
        const float4 o = red[col4];
        acc.x += o.x; acc.y += o.y; acc.z += o.z; acc.w += o.w;
        partial[((long)b * CHF_ + bx) * (C_ / 4) + col4] = acc;
    }
}
__global__ __launch_bounds__(256) void mlp_kernel(
    const float* __restrict__ partial, const float* __restrict__ fc1_w,
    const float* __restrict__ fc1_b, const float* __restrict__ fc2_w,
    const float* __restrict__ fc2_b, float* __restrict__ wbuf)
{
    __shared__ float s_lds[C_];
    __shared__ float y_lds[H_];
    const int b = blockIdx.x, t = threadIdx.x;
    for (int c = t; c < C_; c += 256) {
        float acc = 0.f;
        const float* p = partial + (long)b * CHF_ * C_ + c;
        #pragma unroll
        for (int k = 0; k < CHF_; ++k) acc += p[(long)k * C_];
        s_lds[c] = acc * (1.0f / (float)HW_);
    }
    __syncthreads();
    if (t < H_) {
        float acc = fc1_b[t];
        const float* __restrict__ wr = fc1_w + (long)t * C_;
        #pragma unroll 8
        for (int c = 0; c < C_; ++c) acc += s_lds[c] * wr[c];
        const float x = acc;
        const float u = 0.7978845608028654f * (x + 0.044715f * x * x * x);
        y_lds[t] = 0.5f * x * (1.0f + tanhf(u));
    }
    __syncthreads();
    for (int c = t; c < C_; c += 256) {
        float lg[3];
        #pragma unroll
        for (int j = 0; j < 3; ++j) {
            const int row = j * C_ + c;
            float acc = fc2_b[row];
            const float* __restrict__ wr = fc2_w + (long)row * H_;
            #pragma unroll 8
            for (int h = 0; h < H_; ++h) acc += y_lds[h] * wr[h];
            lg[j] = acc;
        }
        const float m  = fmaxf(lg[0], fmaxf(lg[1], lg[2]));
        const float e0 = __expf(lg[0] - m), e1 = __expf(lg[1] - m), e2 = __expf(lg[2] - m);
        const float inv = 1.0f / (e0 + e1 + e2);
        float* wb = wbuf + (long)b * 3 * C_;
        wb[0 * C_ + c] = e0 * inv; wb[1 * C_ + c] = e1 * inv; wb[2 * C_ + c] = e2 * inv;
    }
}
__global__ __launch_bounds__(256) void out_kernel(
    const float4* __restrict__ c4, const float4* __restrict__ w4,
    const float4* __restrict__ h4, const float4* __restrict__ wb4,
    float4* __restrict__ o4)
{
    const int total = B_ * HW_ * (C_ / 4);
    const int stride = gridDim.x * blockDim.x;
    const int col4 = (blockIdx.x * blockDim.x + threadIdx.x) & 127;
    for (int idx = blockIdx.x * blockDim.x + threadIdx.x; idx < total; idx += stride) {
        const int b = (idx >> 7) / HW_;
        const float4* wb = wb4 + (long)b * (3 * C_ / 4);
        const float4 w0 = wb[col4], w1 = wb[128 + col4], w2 = wb[256 + col4];
        const float4 a = c4[idx], v = w4[idx], u = h4[idx];
        float4 o;
        o.x = a.x * w0.x + v.x * w1.x + u.x * w2.x;
        o.y = a.y * w0.y + v.y * w1.y + u.y * w2.y;
        o.z = a.z * w0.z + v.z * w1.z + u.z * w2.z;
        o.w = a.w * w0.w + v.w * w1.w + u.w * w2.w;
        o4[idx] = o;
    }
}

// ---------------------------------------------------------------------------
extern "C" void kernel_launch(void* const* d_in, const int* in_sizes, int n_in,
                              void* d_out, int out_size, void* d_ws, size_t ws_size,
                              hipStream_t stream)
{
    const float* c_e   = (const float*)d_in[0];
    const float* w_e   = (const float*)d_in[1];
    const float* h_e   = (const float*)d_in[2];
    const float* fc1_w = (const float*)d_in[3];
    const float* fc1_b = (const float*)d_in[4];
    const float* fc2_w = (const float*)d_in[5];
    const float* fc2_b = (const float*)d_in[6];
    float* out = (float*)d_out;

    const size_t partial_bytes = (size_t)2 * NW_ * C_ * 4;      // 4 MB
    const size_t wbuf_bytes    = (size_t)B_ * 3 * C_ * 4;       // 192 KB
    const size_t need          = CTRL_BYTES + partial_bytes + wbuf_bytes;

    if (ws_size >= need) {
        unsigned char* ws = (unsigned char*)d_ws;
        unsigned* ctrl    = (unsigned*)ws;
        float*    partial = (float*)(ws + CTRL_BYTES);
        float*    wbuf    = (float*)(ws + CTRL_BYTES + partial_bytes);
        hipMemsetAsync(ctrl, 0, CTRL_BYTES, stream);
        fused2_kernel<<<NM_ + NW_, 256, 0, stream>>>(
            (const float4*)c_e, (const float4*)w_e, (const float4*)h_e, (float4*)out,
            fc1_w, fc1_b, fc2_w, fc2_b, ctrl, partial, wbuf);
    } else {
        float* partial = (float*)d_ws;
        float* wbuf    = partial + (long)B_ * CHF_ * C_;
        ps_kernel<<<dim3(CHF_, B_), 256, 0, stream>>>(
            (const float4*)c_e, (const float4*)w_e, (const float4*)h_e, (float4*)partial);
        mlp_kernel<<<B_, 256, 0, stream>>>(partial, fc1_w, fc1_b, fc2_w, fc2_b, wbuf);
        out_kernel<<<2048, 256, 0, stream>>>(
            (const float4*)c_e, (const float4*)w_e, (const float4*)h_e,
            (const float4*)wbuf, (float4*)out);
    }
}

// Round 7
// 2692.492 us; speedup vs baseline: 1.1496x; 1.1496x over previous
//
#include <hip/hip_runtime.h>

#define B_    32
#define HW_   3136
#define C_    512
#define H_    128
#define NM_   32                      // MLP blocks (one per batch)
#define NR_   16                      // reducer blocks (stage-2 partial reduce)
#define NW_   1024                    // worker blocks
#define SL_   392                     // float4 slice per worker per batch
#define BPB4_ (HW_ * (C_ / 4))        // float4 per batch = 401408

// ctrl dword offsets (each counter on its own 64 B line):
#define CNT8(b,r)  (16 * ((b) * 8 + (r)))        // 0..4095    worker fold counters
#define CNTB(b)    (4096 + 16 * (b))             // ==8 when all 1024 workers folded b
#define CNT2(b)    (5120 + 16 * (b))             // ==NR_ when stage-2 reduce done
#define FLAG8(b,j) (6144 + 16 * ((b) * 8 + (j))) // weights-ready, replicated x8
#define CTRL_BYTES 40960

__global__ __launch_bounds__(256, 5) void fused3_kernel(
    const float4* __restrict__ c4,
    const float4* __restrict__ w4,
    const float4* __restrict__ h4,
    float4* __restrict__ o4,
    const float* __restrict__ fc1_w,
    const float* __restrict__ fc1_b,
    const float* __restrict__ fc2_w,
    const float* __restrict__ fc2_b,
    unsigned* __restrict__ ctrl,
    float* __restrict__ partial,      // [2][NW_][C_]  double-buffered by b&1
    float* __restrict__ red2,         // [2][NR_][C_]
    float* __restrict__ wbuf)         // [B_][3*C_]
{
    __shared__ float4 stash[3 * SL_ + 128];   // worker: c|w|h slices + red[128]
    const int t = threadIdx.x;

    if (blockIdx.x < NM_) {
        // ================= MLP block: one batch ============================
        const int b = blockIdx.x;
        if (t == 0) {
            unsigned spin = 0;
            while (__hip_atomic_load(&ctrl[CNT2(b)], __ATOMIC_RELAXED,
                                     __HIP_MEMORY_SCOPE_AGENT) != (unsigned)NR_) {
                __builtin_amdgcn_s_sleep(8);
                if (++spin > (1u << 24)) break;
            }
            __builtin_amdgcn_fence(__ATOMIC_ACQUIRE, "agent");
        }
        __syncthreads();

        float* s_lds = (float*)stash;         // [512]
        float* y_lds = ((float*)stash) + C_;  // [128]
        const float* rb = red2 + (size_t)(b & 1) * NR_ * C_;

        for (int c = t; c < C_; c += 256) {
            float a0 = 0.f, a1 = 0.f, a2 = 0.f, a3 = 0.f;
            #pragma unroll
            for (int r = 0; r < NR_; r += 4) {
                a0 += __hip_atomic_load(rb + (size_t)(r + 0) * C_ + c, __ATOMIC_RELAXED, __HIP_MEMORY_SCOPE_AGENT);
                a1 += __hip_atomic_load(rb + (size_t)(r + 1) * C_ + c, __ATOMIC_RELAXED, __HIP_MEMORY_SCOPE_AGENT);
                a2 += __hip_atomic_load(rb + (size_t)(r + 2) * C_ + c, __ATOMIC_RELAXED, __HIP_MEMORY_SCOPE_AGENT);
                a3 += __hip_atomic_load(rb + (size_t)(r + 3) * C_ + c, __ATOMIC_RELAXED, __HIP_MEMORY_SCOPE_AGENT);
            }
            s_lds[c] = ((a0 + a1) + (a2 + a3)) * (1.0f / (float)HW_);
        }
        __syncthreads();

        if (t < H_) {
            float acc = fc1_b[t];
            const float* __restrict__ wr = fc1_w + (long)t * C_;
            #pragma unroll 4
            for (int c = 0; c < C_; ++c) acc += s_lds[c] * wr[c];
            const float x = acc;
            const float u = 0.7978845608028654f * (x + 0.044715f * x * x * x);
            y_lds[t] = 0.5f * x * (1.0f + tanhf(u));
        }
        __syncthreads();

        for (int c = t; c < C_; c += 256) {
            float lg[3];
            #pragma unroll
            for (int j = 0; j < 3; ++j) {
                const int row = j * C_ + c;
                float a2c = fc2_b[row];
                const float* __restrict__ wr = fc2_w + (long)row * H_;
                #pragma unroll 4
                for (int h = 0; h < H_; ++h) a2c += y_lds[h] * wr[h];
                lg[j] = a2c;
            }
            const float m  = fmaxf(lg[0], fmaxf(lg[1], lg[2]));
            const float e0 = __expf(lg[0] - m);
            const float e1 = __expf(lg[1] - m);
            const float e2 = __expf(lg[2] - m);
            const float inv = 1.0f / (e0 + e1 + e2);
            float* wb = wbuf + (long)b * 3 * C_;
            __hip_atomic_store(wb + 0 * C_ + c, e0 * inv, __ATOMIC_RELAXED, __HIP_MEMORY_SCOPE_AGENT);
            __hip_atomic_store(wb + 1 * C_ + c, e1 * inv, __ATOMIC_RELAXED, __HIP_MEMORY_SCOPE_AGENT);
            __hip_atomic_store(wb + 2 * C_ + c, e2 * inv, __ATOMIC_RELAXED, __HIP_MEMORY_SCOPE_AGENT);
        }
        __syncthreads();
        if (t < 8)
            __hip_atomic_store(&ctrl[FLAG8(b, t)], 1u, __ATOMIC_RELEASE, __HIP_MEMORY_SCOPE_AGENT);
        return;
    }

    if (blockIdx.x < NM_ + NR_) {
        // ================= reducer block: stage-2 over 64 workers ==========
        const int r = blockIdx.x - NM_;        // 0..15
        for (int b = 0; b < B_; ++b) {
            if (t == 0) {
                unsigned spin = 0;
                while (__hip_atomic_load(&ctrl[CNTB(b)], __ATOMIC_RELAXED,
                                         __HIP_MEMORY_SCOPE_AGENT) != 8u) {
                    __builtin_amdgcn_s_sleep(8);
                    if (++spin > (1u << 24)) break;
                }
                __builtin_amdgcn_fence(__ATOMIC_ACQUIRE, "agent");
            }
            __syncthreads();
            const float* pb = partial + (size_t)(b & 1) * NW_ * C_ + (size_t)r * 64 * C_;
            float* rb = red2 + (size_t)(b & 1) * NR_ * C_ + (size_t)r * C_;
            #pragma unroll
            for (int half = 0; half < 2; ++half) {
                const int c = t + half * 256;
                float s0=0.f,s1=0.f,s2=0.f,s3=0.f,s4=0.f,s5=0.f,s6=0.f,s7=0.f;
                #pragma unroll
                for (int w = 0; w < 64; w += 8) {
                    s0 += __hip_atomic_load(pb + (size_t)(w + 0) * C_ + c, __ATOMIC_RELAXED, __HIP_MEMORY_SCOPE_AGENT);
                    s1 += __hip_atomic_load(pb + (size_t)(w + 1) * C_ + c, __ATOMIC_RELAXED, __HIP_MEMORY_SCOPE_AGENT);
                    s2 += __hip_atomic_load(pb + (size_t)(w + 2) * C_ + c, __ATOMIC_RELAXED, __HIP_MEMORY_SCOPE_AGENT);
                    s3 += __hip_atomic_load(pb + (size_t)(w + 3) * C_ + c, __ATOMIC_RELAXED, __HIP_MEMORY_SCOPE_AGENT);
                    s4 += __hip_atomic_load(pb + (size_t)(w + 4) * C_ + c, __ATOMIC_RELAXED, __HIP_MEMORY_SCOPE_AGENT);
                    s5 += __hip_atomic_load(pb + (size_t)(w + 5) * C_ + c, __ATOMIC_RELAXED, __HIP_MEMORY_SCOPE_AGENT);
                    s6 += __hip_atomic_load(pb + (size_t)(w + 6) * C_ + c, __ATOMIC_RELAXED, __HIP_MEMORY_SCOPE_AGENT);
                    s7 += __hip_atomic_load(pb + (size_t)(w + 7) * C_ + c, __ATOMIC_RELAXED, __HIP_MEMORY_SCOPE_AGENT);
                }
                const float s = ((s0 + s1) + (s2 + s3)) + ((s4 + s5) + (s6 + s7));
                __hip_atomic_store(rb + c, s, __ATOMIC_RELAXED, __HIP_MEMORY_SCOPE_AGENT);
            }
            __syncthreads();
            if (t == 0)
                __hip_atomic_fetch_add(&ctrl[CNT2(b)], 1u,
                                       __ATOMIC_ACQ_REL, __HIP_MEMORY_SCOPE_AGENT);
        }
        return;
    }

    // ==================== worker block =====================================
    const int wid  = blockIdx.x - NM_ - NR_;    // 0..1023
    const int col4 = (8 * wid + t) & 127;       // same for elem t and t+256
    const bool two = (t < SL_ - 256);           // t < 136 handles 2nd element
    float4* sc  = stash;
    float4* sw  = stash + SL_;
    float4* sh  = stash + 2 * SL_;
    float4* red = stash + 3 * SL_;

    float4 a0, v0, u0, a1, v1, u1;

    #define LOAD_FOLD_SIGNAL(bb)                                                  \
    {                                                                             \
        const long g = (long)(bb) * BPB4_ + (long)wid * SL_;                      \
        a0 = c4[g + t]; v0 = w4[g + t]; u0 = h4[g + t];                           \
        if (two) { a1 = c4[g + t + 256]; v1 = w4[g + t + 256]; u1 = h4[g + t + 256]; } \
        float4 acc;                                                               \
        acc.x = a0.x + v0.x + u0.x; acc.y = a0.y + v0.y + u0.y;                   \
        acc.z = a0.z + v0.z + u0.z; acc.w = a0.w + v0.w + u0.w;                   \
        if (two) {                                                                \
            acc.x += a1.x + v1.x + u1.x; acc.y += a1.y + v1.y + u1.y;             \
            acc.z += a1.z + v1.z + u1.z; acc.w += a1.w + v1.w + u1.w;             \
        }                                                                         \
        if (t >= 128) red[t - 128] = acc;                                         \
        __syncthreads();                                                          \
        if (t < 128) {                                                            \
            const float4 o = red[t];                                              \
            acc.x += o.x; acc.y += o.y; acc.z += o.z; acc.w += o.w;               \
            float* pp = partial + (size_t)((bb) & 1) * NW_ * C_                   \
                      + (size_t)wid * C_ + col4 * 4;                              \
            __hip_atomic_store(pp + 0, acc.x, __ATOMIC_RELAXED, __HIP_MEMORY_SCOPE_AGENT); \
            __hip_atomic_store(pp + 1, acc.y, __ATOMIC_RELAXED, __HIP_MEMORY_SCOPE_AGENT); \
            __hip_atomic_store(pp + 2, acc.z, __ATOMIC_RELAXED, __HIP_MEMORY_SCOPE_AGENT); \
            __hip_atomic_store(pp + 3, acc.w, __ATOMIC_RELAXED, __HIP_MEMORY_SCOPE_AGENT); \
        }                                                                         \
        __syncthreads();                                                          \
        if (t == 0) {                                                             \
            const unsigned old = __hip_atomic_fetch_add(                          \
                &ctrl[CNT8((bb), wid & 7)], 1u, __ATOMIC_ACQ_REL, __HIP_MEMORY_SCOPE_AGENT); \
            if (old == 127u)                                                      \
                __hip_atomic_fetch_add(&ctrl[CNTB(bb)], 1u,                       \
                                       __ATOMIC_ACQ_REL, __HIP_MEMORY_SCOPE_AGENT); \
        }                                                                         \
    }

    #define DUMP_TO_LDS()                                                         \
    {                                                                             \
        sc[t] = a0; sw[t] = v0; sh[t] = u0;                                       \
        if (two) { sc[t + 256] = a1; sw[t + 256] = v1; sh[t + 256] = u1; }        \
    }

    LOAD_FOLD_SIGNAL(0);
    DUMP_TO_LDS();

    for (int b = 0; b < B_; ++b) {
        if (b + 1 < B_) LOAD_FOLD_SIGNAL(b + 1);

        if (t == 0) {
            unsigned spin = 0;
            while (__hip_atomic_load(&ctrl[FLAG8(b, wid & 7)], __ATOMIC_RELAXED,
                                     __HIP_MEMORY_SCOPE_AGENT) == 0u) {
                __builtin_amdgcn_s_sleep(8);
                if (++spin > (1u << 24)) break;
            }
            __builtin_amdgcn_fence(__ATOMIC_ACQUIRE, "agent");
        }
        __syncthreads();

        const float* wb = wbuf + (long)b * 3 * C_ + col4 * 4;
        float w0[4], w1[4], w2[4];
        #pragma unroll
        for (int j = 0; j < 4; ++j) {
            w0[j] = __hip_atomic_load(wb + 0 * C_ + j, __ATOMIC_RELAXED, __HIP_MEMORY_SCOPE_AGENT);
            w1[j] = __hip_atomic_load(wb + 1 * C_ + j, __ATOMIC_RELAXED, __HIP_MEMORY_SCOPE_AGENT);
            w2[j] = __hip_atomic_load(wb + 2 * C_ + j, __ATOMIC_RELAXED, __HIP_MEMORY_SCOPE_AGENT);
        }

        const long obase = (long)b * BPB4_ + (long)wid * SL_;
        {
            const float4 A = sc[t], V = sw[t], U = sh[t];
            float4 o;
            o.x = A.x * w0[0] + V.x * w1[0] + U.x * w2[0];
            o.y = A.y * w0[1] + V.y * w1[1] + U.y * w2[1];
            o.z = A.z * w0[2] + V.z * w1[2] + U.z * w2[2];
            o.w = A.w * w0[3] + V.w * w1[3] + U.w * w2[3];
            o4[obase + t] = o;
        }
        if (two) {
            const float4 A = sc[t + 256], V = sw[t + 256], U = sh[t + 256];
            float4 o;
            o.x = A.x * w0[0] + V.x * w1[0] + U.x * w2[0];
            o.y = A.y * w0[1] + V.y * w1[1] + U.y * w2[1];
            o.z = A.z * w0[2] + V.z * w1[2] + U.z * w2[2];
            o.w = A.w * w0[3] + V.w * w1[3] + U.w * w2[3];
            o4[obase + t + 256] = o;
        }

        if (b + 1 < B_) DUMP_TO_LDS();   // own slots; pass2 of b already consumed them
    }
    #undef LOAD_FOLD_SIGNAL
    #undef DUMP_TO_LDS
}

// ===========================================================================
// Fallback: proven R3 three-kernel path (330 us) if workspace is too small.
// ===========================================================================
#define CHF_ 49
__global__ __launch_bounds__(256) void ps_kernel(
    const float4* __restrict__ c4, const float4* __restrict__ w4,
    const float4* __restrict__ h4, float4* __restrict__ partial)
{
    const int bx = blockIdx.x, b = blockIdx.y, t = threadIdx.x;
    const int col4 = t & 127, rl = t >> 7;
    const int STRIDE = CHF_ * 256;
    long idx = (long)b * BPB4_ + bx * 256 + t;
    float4 acc = make_float4(0.f, 0.f, 0.f, 0.f);
    #pragma unroll 4
    for (int it = 0; it < 32; ++it) {
        const float4 a = c4[idx], v = w4[idx], u = h4[idx];
        acc.x += a.x + v.x + u.x; acc.y += a.y + v.y + u.y;
        acc.z += a.z + v.z + u.z; acc.w += a.w + v.w + u.w;
        idx += STRIDE;
    }
    __shared__ float4 red[128];
    if (rl == 1) red[col4] = acc;
    __syncthreads();
    if (rl == 0) {
        const float4 o = red[col4];
        acc.x += o.x; acc.y += o.y; acc.z += o.z; acc.w += o.w;
        partial[((long)b * CHF_ + bx) * (C_ / 4) + col4] = acc;
    }
}
__global__ __launch_bounds__(256) void mlp_kernel(
    const float* __restrict__ partial, const float* __restrict__ fc1_w,
    const float* __restrict__ fc1_b, const float* __restrict__ fc2_w,
    const float* __restrict__ fc2_b, float* __restrict__ wbuf)
{
    __shared__ float s_lds[C_];
    __shared__ float y_lds[H_];
    const int b = blockIdx.x, t = threadIdx.x;
    for (int c = t; c < C_; c += 256) {
        float acc = 0.f;
        const float* p = partial + (long)b * CHF_ * C_ + c;
        #pragma unroll
        for (int k = 0; k < CHF_; ++k) acc += p[(long)k * C_];
        s_lds[c] = acc * (1.0f / (float)HW_);
    }
    __syncthreads();
    if (t < H_) {
        float acc = fc1_b[t];
        const float* __restrict__ wr = fc1_w + (long)t * C_;
        #pragma unroll 8
        for (int c = 0; c < C_; ++c) acc += s_lds[c] * wr[c];
        const float x = acc;
        const float u = 0.7978845608028654f * (x + 0.044715f * x * x * x);
        y_lds[t] = 0.5f * x * (1.0f + tanhf(u));
    }
    __syncthreads();
    for (int c = t; c < C_; c += 256) {
        float lg[3];
        #pragma unroll
        for (int j = 0; j < 3; ++j) {
            const int row = j * C_ + c;
            float acc = fc2_b[row];
            const float* __restrict__ wr = fc2_w + (long)row * H_;
            #pragma unroll 8
            for (int h = 0; h < H_; ++h) acc += y_lds[h] * wr[h];
            lg[j] = acc;
        }
        const float m  = fmaxf(lg[0], fmaxf(lg[1], lg[2]));
        const float e0 = __expf(lg[0] - m), e1 = __expf(lg[1] - m), e2 = __expf(lg[2] - m);
        const float inv = 1.0f / (e0 + e1 + e2);
        float* wb = wbuf + (long)b * 3 * C_;
        wb[0 * C_ + c] = e0 * inv; wb[1 * C_ + c] = e1 * inv; wb[2 * C_ + c] = e2 * inv;
    }
}
__global__ __launch_bounds__(256) void out_kernel(
    const float4* __restrict__ c4, const float4* __restrict__ w4,
    const float4* __restrict__ h4, const float4* __restrict__ wb4,
    float4* __restrict__ o4)
{
    const int total = B_ * HW_ * (C_ / 4);
    const int stride = gridDim.x * blockDim.x;
    const int col4 = (blockIdx.x * blockDim.x + threadIdx.x) & 127;
    for (int idx = blockIdx.x * blockDim.x + threadIdx.x; idx < total; idx += stride) {
        const int b = (idx >> 7) / HW_;
        const float4* wb = wb4 + (long)b * (3 * C_ / 4);
        const float4 w0 = wb[col4], w1 = wb[128 + col4], w2 = wb[256 + col4];
        const float4 a = c4[idx], v = w4[idx], u = h4[idx];
        float4 o;
        o.x = a.x * w0.x + v.x * w1.x + u.x * w2.x;
        o.y = a.y * w0.y + v.y * w1.y + u.y * w2.y;
        o.z = a.z * w0.z + v.z * w1.z + u.z * w2.z;
        o.w = a.w * w0.w + v.w * w1.w + u.w * w2.w;
        o4[idx] = o;
    }
}

// ---------------------------------------------------------------------------
extern "C" void kernel_launch(void* const* d_in, const int* in_sizes, int n_in,
                              void* d_out, int out_size, void* d_ws, size_t ws_size,
                              hipStream_t stream)
{
    const float* c_e   = (const float*)d_in[0];
    const float* w_e   = (const float*)d_in[1];
    const float* h_e   = (const float*)d_in[2];
    const float* fc1_w = (const float*)d_in[3];
    const float* fc1_b = (const float*)d_in[4];
    const float* fc2_w = (const float*)d_in[5];
    const float* fc2_b = (const float*)d_in[6];
    float* out = (float*)d_out;

    const size_t partial_bytes = (size_t)2 * NW_ * C_ * 4;      // 4 MB
    const size_t red2_bytes    = (size_t)2 * NR_ * C_ * 4;      // 64 KB
    const size_t wbuf_bytes    = (size_t)B_ * 3 * C_ * 4;       // 192 KB
    const size_t need = CTRL_BYTES + partial_bytes + red2_bytes + wbuf_bytes;

    if (ws_size >= need) {
        unsigned char* ws = (unsigned char*)d_ws;
        unsigned* ctrl    = (unsigned*)ws;
        float*    partial = (float*)(ws + CTRL_BYTES);
        float*    red2    = (float*)(ws + CTRL_BYTES + partial_bytes);
        float*    wbuf    = (float*)(ws + CTRL_BYTES + partial_bytes + red2_bytes);
        hipMemsetAsync(ctrl, 0, CTRL_BYTES, stream);
        fused3_kernel<<<NM_ + NR_ + NW_, 256, 0, stream>>>(
            (const float4*)c_e, (const float4*)w_e, (const float4*)h_e, (float4*)out,
            fc1_w, fc1_b, fc2_w, fc2_b, ctrl, partial, red2, wbuf);
    } else {
        float* partial = (float*)d_ws;
        float* wbuf    = partial + (long)B_ * CHF_ * C_;
        ps_kernel<<<dim3(CHF_, B_), 256, 0, stream>>>(
            (const float4*)c_e, (const float4*)w_e, (const float4*)h_e, (float4*)partial);
        mlp_kernel<<<B_, 256, 0, stream>>>(partial, fc1_w, fc1_b, fc2_w, fc2_b, wbuf);
        out_kernel<<<2048, 256, 0, stream>>>(
            (const float4*)c_e, (const float4*)w_e, (const float4*)h_e,
            (const float4*)wbuf, (float4*)out);
    }
}

// Round 9
// 359.534 us; speedup vs baseline: 8.6090x; 7.4888x over previous
//
#include <hip/hip_runtime.h>

#define B_   32
#define HW_  3136
#define C_   512
#define H_   128

typedef float nfloat4 __attribute__((ext_vector_type(4)));   // native vec for nt-store

// ---------------------------------------------------------------------------
// Kernel 1: per-(batch, chunk) column sums of (c + w + h).   [R2 verbatim: 163us]
// Grid: dim3(CH, B_), 256 threads = 2 rows x 128 float4-columns.
// ---------------------------------------------------------------------------
__global__ __launch_bounds__(256) void ps_kernel(
    const float4* __restrict__ c4,
    const float4* __restrict__ w4,
    const float4* __restrict__ h4,
    float4* __restrict__ partial,
    int rows)                               // rows per chunk (HW_ / CH)
{
    const int k    = blockIdx.x;            // chunk
    const int b    = blockIdx.y;            // batch
    const int CH   = gridDim.x;
    const int col4 = threadIdx.x & 127;     // float4 column (128 * 4 = 512)
    const int rl   = threadIdx.x >> 7;      // row-local 0/1

    long base = ((long)b * HW_ + (long)k * rows + rl) * (C_ / 4) + col4;
    float4 acc = make_float4(0.f, 0.f, 0.f, 0.f);

    #pragma unroll 4
    for (int r = 0; r < rows; r += 2) {
        const float4 a = c4[base];
        const float4 v = w4[base];
        const float4 u = h4[base];
        acc.x += a.x + v.x + u.x;
        acc.y += a.y + v.y + u.y;
        acc.z += a.z + v.z + u.z;
        acc.w += a.w + v.w + u.w;
        base += 2 * (C_ / 4);
    }

    __shared__ float4 red[128];
    if (rl == 1) red[col4] = acc;
    __syncthreads();
    if (rl == 0) {
        const float4 o = red[col4];
        acc.x += o.x; acc.y += o.y; acc.z += o.z; acc.w += o.w;
        partial[((long)b * CH + k) * (C_ / 4) + col4] = acc;
    }
}

// ---------------------------------------------------------------------------
// Kernel 2: reduce partials -> mean; fc1 + tanh-GELU; fc2; 3-way softmax.
// One block per batch, 256 threads.                         [R2 verbatim]
// ---------------------------------------------------------------------------
__global__ __launch_bounds__(256) void mlp_kernel(
    const float* __restrict__ partial,
    const float* __restrict__ fc1_w,
    const float* __restrict__ fc1_b,
    const float* __restrict__ fc2_w,
    const float* __restrict__ fc2_b,
    float* __restrict__ wbuf,
    int CH)
{
    __shared__ float s_lds[C_];
    __shared__ float y_lds[H_];

    const int b = blockIdx.x;
    const int t = threadIdx.x;

    for (int c = t; c < C_; c += 256) {
        float acc = 0.f;
        const float* __restrict__ p = partial + (long)b * CH * C_ + c;
        for (int k = 0; k < CH; ++k) acc += p[(long)k * C_];
        s_lds[c] = acc * (1.0f / (float)HW_);
    }
    __syncthreads();

    if (t < H_) {
        float acc = fc1_b[t];
        const float* __restrict__ wr = fc1_w + (long)t * C_;
        #pragma unroll 8
        for (int c = 0; c < C_; ++c) acc += s_lds[c] * wr[c];
        const float x = acc;
        const float u = 0.7978845608028654f * (x + 0.044715f * x * x * x);
        y_lds[t] = 0.5f * x * (1.0f + tanhf(u));
    }
    __syncthreads();

    for (int c = t; c < C_; c += 256) {
        float lg[3];
        #pragma unroll
        for (int j = 0; j < 3; ++j) {
            const int row = j * C_ + c;
            float acc = fc2_b[row];
            const float* __restrict__ wr = fc2_w + (long)row * H_;
            #pragma unroll 8
            for (int h = 0; h < H_; ++h) acc += y_lds[h] * wr[h];
            lg[j] = acc;
        }
        const float m  = fmaxf(lg[0], fmaxf(lg[1], lg[2]));
        const float e0 = __expf(lg[0] - m);
        const float e1 = __expf(lg[1] - m);
        const float e2 = __expf(lg[2] - m);
        const float inv = 1.0f / (e0 + e1 + e2);
        float* __restrict__ wb = wbuf + (long)b * 3 * C_;
        wb[0 * C_ + c] = e0 * inv;
        wb[1 * C_ + c] = e1 * inv;
        wb[2 * C_ + c] = e2 * inv;
    }
}

// ---------------------------------------------------------------------------
// Kernel 3: out = c*w0 + w*w1 + h*w2.  Flat grid-stride swept in REVERSE:
// ps ends with the arrays' tail (~250 MB) L3-resident, so starting from the
// high addresses converts the first ~40% of reads into L3 hits. Output is
// stored nontemporally (never re-read) so the 205 MB of writes don't evict
// the resident read lines.
// ---------------------------------------------------------------------------
__global__ __launch_bounds__(256) void out_kernel(
    const float4* __restrict__ c4,
    const float4* __restrict__ w4,
    const float4* __restrict__ h4,
    const float4* __restrict__ wb4,
    float4* __restrict__ o4)
{
    const long total  = (long)B_ * HW_ * (C_ / 4);    // 12,845,056
    const long stride = (long)gridDim.x * blockDim.x; // 524,288 (%128==0)
    const long gid    = (long)blockIdx.x * blockDim.x + threadIdx.x;
    const int  col4   = (int)(gid & 127);

    nfloat4* __restrict__ on = (nfloat4*)o4;

    // highest k with any coverage: k = 24 (ceil(total/stride)-1)
    for (long idx = gid + 24L * stride; idx >= 0; idx -= stride) {
        if (idx < total) {
            const int b = (int)((idx >> 7) / HW_);
            const float4* __restrict__ wb = wb4 + (long)b * (3 * C_ / 4);
            const float4 w0 = wb[col4];
            const float4 w1 = wb[128 + col4];
            const float4 w2 = wb[256 + col4];
            const float4 a = c4[idx];
            const float4 v = w4[idx];
            const float4 u = h4[idx];
            nfloat4 o;
            o.x = a.x * w0.x + v.x * w1.x + u.x * w2.x;
            o.y = a.y * w0.y + v.y * w1.y + u.y * w2.y;
            o.z = a.z * w0.z + v.z * w1.z + u.z * w2.z;
            o.w = a.w * w0.w + v.w * w1.w + u.w * w2.w;
            __builtin_nontemporal_store(o, &on[idx]);
        }
    }
}

// ---------------------------------------------------------------------------
extern "C" void kernel_launch(void* const* d_in, const int* in_sizes, int n_in,
                              void* d_out, int out_size, void* d_ws, size_t ws_size,
                              hipStream_t stream)
{
    const float* c_e   = (const float*)d_in[0];
    const float* w_e   = (const float*)d_in[1];
    const float* h_e   = (const float*)d_in[2];
    const float* fc1_w = (const float*)d_in[3];
    const float* fc1_b = (const float*)d_in[4];
    const float* fc2_w = (const float*)d_in[5];
    const float* fc2_b = (const float*)d_in[6];
    float* out = (float*)d_out;

    // choose chunks/batch from available workspace (partial + wbuf, floats)
    int CH = 98;
    {
        const size_t need98 = ((size_t)B_ * 98 * C_ + (size_t)B_ * 3 * C_) * 4;
        const size_t need49 = ((size_t)B_ * 49 * C_ + (size_t)B_ * 3 * C_) * 4;
        if (ws_size < need98) CH = 49;
        if (ws_size < need49) CH = 32;
    }
    const int rows = HW_ / CH;   // 32 / 64 / 98 (all even)

    float* partial = (float*)d_ws;
    float* wbuf    = partial + (long)B_ * CH * C_;

    ps_kernel<<<dim3(CH, B_), 256, 0, stream>>>(
        (const float4*)c_e, (const float4*)w_e, (const float4*)h_e,
        (float4*)partial, rows);
    mlp_kernel<<<B_, 256, 0, stream>>>(partial, fc1_w, fc1_b, fc2_w, fc2_b, wbuf, CH);
    out_kernel<<<2048, 256, 0, stream>>>(
        (const float4*)c_e, (const float4*)w_e, (const float4*)h_e,
        (const float4*)wbuf, (float4*)out);
}